// Round 3
// baseline (523.201 us; speedup 1.0000x reference)
//
#include <hip/hip_runtime.h>
#include <hip/hip_fp16.h>
#include <stdint.h>

// Problem constants
#define BS 6
#define NQ 4096
#define NH 8
#define EMB 256
#define LTOT 19560
#define ROWS_V 117360
#define ROWS_VP 117376          // padded to 917*128
#define ROWS_Q 24576            // 192*128

typedef __attribute__((ext_vector_type(8))) short bf16x8;
typedef __attribute__((ext_vector_type(4))) float floatx4;
typedef __attribute__((ext_vector_type(8))) unsigned short ushort8v;

__device__ __forceinline__ ushort f2bf(float f) {
    union { float f; uint32_t i; } c; c.f = f;
    uint32_t r = c.i + 0x7FFFu + ((c.i >> 16) & 1u);   // round-to-nearest-even
    return (ushort)(r >> 16);
}
__device__ __forceinline__ ushort f2h(float f) {
    __half h = __float2half(f);                        // RTE
    union { __half h; ushort u; } c; c.h = h; return c.u;
}

__device__ __forceinline__ void gll16(const ushort* g, ushort* l) {
    __builtin_amdgcn_global_load_lds(
        (const __attribute__((address_space(1))) void*)g,
        (__attribute__((address_space(3))) void*)l, 16, 0, 0);
}

// compile-time broadcast of lane L (within each 4-lane group) via ds_swizzle
// BitMode offset: [14:10]=xor [9:5]=or [4:0]=and ; src = ((lane&0x1C)|L)
template<int L>
__device__ __forceinline__ float bcastf(float x) {
    return __int_as_float(
        __builtin_amdgcn_ds_swizzle(__float_as_int(x), 0x1C | (L << 5)));
}
template<int L>
__device__ __forceinline__ uint32_t bcastu(uint32_t x) {
    return (uint32_t)__builtin_amdgcn_ds_swizzle((int)x, 0x1C | (L << 5));
}

// gfx950 mixed-precision FMA: acc = f32(w) * f16half(u) + acc
__device__ __forceinline__ void fmx_lo(float& acc, float w, uint32_t u) {
    asm("v_fma_mix_f32 %0, %1, %2, %0 op_sel:[0,0,0] op_sel_hi:[0,1,0]"
        : "+v"(acc) : "v"(w), "v"(u));
}
__device__ __forceinline__ void fmx_hi(float& acc, float w, uint32_t u) {
    asm("v_fma_mix_f32 %0, %1, %2, %0 op_sel:[0,1,0] op_sel_hi:[0,1,0]"
        : "+v"(acc) : "v"(w), "v"(u));
}

// ---------------------------------------------------------------------------
// fp32 -> bf16 cast (row-contiguous), 8 elems/thread
// ---------------------------------------------------------------------------
__global__ __launch_bounds__(256) void cast_bf16(
    const float* __restrict__ in, ushort* __restrict__ out, int n)
{
    int i = (blockIdx.x * 256 + threadIdx.x) * 8;
    if (i >= n) return;
    float4 f0 = *(const float4*)(in + i);
    float4 f1 = *(const float4*)(in + i + 4);
    ushort8v r;
    r[0] = f2bf(f0.x); r[1] = f2bf(f0.y); r[2] = f2bf(f0.z); r[3] = f2bf(f0.w);
    r[4] = f2bf(f1.x); r[5] = f2bf(f1.y); r[6] = f2bf(f1.z); r[7] = f2bf(f1.w);
    *(ushort8v*)(out + i) = r;
}

// ---------------------------------------------------------------------------
// W (K=256 x N) fp32  ->  Wt (N x 256) bf16   (tiny matrices)
// ---------------------------------------------------------------------------
__global__ __launch_bounds__(256) void cast_t(
    const float* __restrict__ W, ushort* __restrict__ Wt, int N_)
{
    int id = blockIdx.x * 256 + threadIdx.x;
    if (id >= 256 * N_) return;
    int n = id >> 8;         // / 256 (K = 256)
    int k = id & 255;
    Wt[id] = f2bf(W[(size_t)k * N_ + n]);
}

__global__ __launch_bounds__(768) void bias_concat(
    const float* __restrict__ b_off, const float* __restrict__ b_attn,
    float* __restrict__ bcat)
{
    int i = threadIdx.x;
    bcat[i] = (i < 512) ? b_off[i] : b_attn[i - 512];
}

// ---------------------------------------------------------------------------
// Fused value GEMM: v = value(fp32) @ Wvt^T + b_val -> fp16, PER-HEAD layout:
//   out[((b*8 + head)*LTOT + pixel)*32 + ch]   (64 B per (head,pixel))
// Block: 512 threads = 8 waves (2x4), tile 128(M) x 256(N=full), BK=32.
// ---------------------------------------------------------------------------
__global__ __launch_bounds__(512) void vgemm(
    const float* __restrict__ A,     // ROWS_V x 256 fp32
    const ushort* __restrict__ Bt,   // 256 x 256 bf16
    const float* __restrict__ bias,  // 256
    ushort* __restrict__ C)          // per-head fp16 table
{
    constexpr int K = 256, M = ROWS_V;
    __shared__ ushort As[128 * 32];
    __shared__ ushort Bs[256 * 32];

    const int t = threadIdx.x;
    const int w = t >> 6;
    const int lane = t & 63;
    const int bm = blockIdx.x * 128;
    const int wm = (w >> 2) * 64;
    const int wn = (w & 3) * 64;

    // A staging: thread t -> row t>>2 (0..127), cols (t&3)*8 .. +8
    const int arow = t >> 2;
    const int acol = (t & 3) * 8;
    const bool rowok = (bm + arow) < M;
    const float* Ap = A + (size_t)(bm + arow) * K + acol;
    ushort* Asw = &As[arow * 32 + acol];

    // B staging: wave w stages rows [32w, 32w+32) in two 16-row chunks
    const int srow = lane >> 2;
    const int scol = (lane & 3) * 8;
    const ushort* Bg0 = Bt + (size_t)(w * 32 + srow) * K + scol;
    const ushort* Bg1 = Bt + (size_t)(w * 32 + 16 + srow) * K + scol;
    ushort* Bl0 = &Bs[(w * 32) * 32];
    ushort* Bl1 = &Bs[(w * 32 + 16) * 32];

    const ushort* apt = &As[(wm + (lane & 15)) * 32 + (lane >> 4) * 8];
    const ushort* bpt = &Bs[(wn + (lane & 15)) * 32 + (lane >> 4) * 8];

    floatx4 acc[4][4] = {};

    for (int kt = 0; kt < K; kt += 32) {
        float4 f0, f1;
        if (rowok) {
            f0 = *(const float4*)(Ap + kt);
            f1 = *(const float4*)(Ap + kt + 4);
        } else {
            f0 = make_float4(0.f, 0.f, 0.f, 0.f);
            f1 = f0;
        }
        __syncthreads();   // previous iter's fragment reads done
        gll16(Bg0 + kt, Bl0);
        gll16(Bg1 + kt, Bl1);
        ushort8v u;
        u[0] = f2bf(f0.x); u[1] = f2bf(f0.y); u[2] = f2bf(f0.z); u[3] = f2bf(f0.w);
        u[4] = f2bf(f1.x); u[5] = f2bf(f1.y); u[6] = f2bf(f1.z); u[7] = f2bf(f1.w);
        *(ushort8v*)Asw = u;
        __syncthreads();   // staging visible (drains vmcnt + lgkmcnt)

        bf16x8 a[4], b[4];
        #pragma unroll
        for (int i = 0; i < 4; ++i) {
            a[i] = *(const bf16x8*)(apt + i * 16 * 32);
            b[i] = *(const bf16x8*)(bpt + i * 16 * 32);
        }
        #pragma unroll
        for (int i = 0; i < 4; ++i)
            #pragma unroll
            for (int j = 0; j < 4; ++j)
                acc[i][j] = __builtin_amdgcn_mfma_f32_16x16x32_bf16(
                    a[i], b[j], acc[i][j], 0, 0, 0);
    }

    const int crow = (lane >> 4) * 4;
    const int ccol = lane & 15;
    #pragma unroll
    for (int j = 0; j < 4; ++j) {
        int gcol = wn + j * 16 + ccol;
        float bv = bias[gcol];
        int hh = gcol >> 5;          // head
        int cc = gcol & 31;          // channel within head
        #pragma unroll
        for (int i = 0; i < 4; ++i) {
            #pragma unroll
            for (int r = 0; r < 4; ++r) {
                int grow = bm + wm + i * 16 + crow + r;
                if (grow < M) {
                    int bb = grow / LTOT;          // magic-mul div
                    int p  = grow - bb * LTOT;
                    C[((size_t)((bb << 3) + hh) * LTOT + p) * 32 + cc] =
                        f2h(acc[i][j][r] + bv);
                }
            }
        }
    }
}

// ---------------------------------------------------------------------------
// bf16 MFMA GEMM (m97 structure): C[M,N] = A[M,256] @ Bt[N,256]^T + bias
// fp32 output. 128x128 tile, 256 threads = 4 waves.
// ---------------------------------------------------------------------------
__global__ __launch_bounds__(256) void gemm_bt(
    const ushort* __restrict__ A,    // Mpad x 256 bf16
    const ushort* __restrict__ Bt,   // N x 256 bf16
    const float* __restrict__ bias,  // N
    float* __restrict__ C, int M, int N)
{
    constexpr int K = 256;
    __shared__ ushort As[128 * 32];
    __shared__ ushort Bs[128 * 32];

    const int t = threadIdx.x;
    const int w = t >> 6;
    const int lane = t & 63;
    const int bm = blockIdx.x * 128;
    const int bn = blockIdx.y * 128;
    const int wm = (w >> 1) * 64;
    const int wn = (w & 1) * 64;

    floatx4 acc[4][4] = {};

    const int srow = lane >> 2;
    const int scol = (lane & 3) * 8;
    const ushort* Ag0 = A + (size_t)(bm + (w * 2 + 0) * 16 + srow) * K + scol;
    const ushort* Ag1 = A + (size_t)(bm + (w * 2 + 1) * 16 + srow) * K + scol;
    const ushort* Bg0 = Bt + (size_t)(bn + (w * 2 + 0) * 16 + srow) * K + scol;
    const ushort* Bg1 = Bt + (size_t)(bn + (w * 2 + 1) * 16 + srow) * K + scol;
    ushort* Al0 = &As[(w * 2 + 0) * 512];
    ushort* Al1 = &As[(w * 2 + 1) * 512];
    ushort* Bl0 = &Bs[(w * 2 + 0) * 512];
    ushort* Bl1 = &Bs[(w * 2 + 1) * 512];

    const ushort* apt = &As[(wm + (lane & 15)) * 32 + (lane >> 4) * 8];
    const ushort* bpt = &Bs[(wn + (lane & 15)) * 32 + (lane >> 4) * 8];

    for (int kt = 0; kt < K; kt += 32) {
        __syncthreads();
        gll16(Ag0 + kt, Al0);
        gll16(Ag1 + kt, Al1);
        gll16(Bg0 + kt, Bl0);
        gll16(Bg1 + kt, Bl1);
        __syncthreads();

        bf16x8 a[4], b[4];
        #pragma unroll
        for (int i = 0; i < 4; ++i) {
            a[i] = *(const bf16x8*)(apt + i * 16 * 32);
            b[i] = *(const bf16x8*)(bpt + i * 16 * 32);
        }
        #pragma unroll
        for (int i = 0; i < 4; ++i)
            #pragma unroll
            for (int j = 0; j < 4; ++j)
                acc[i][j] = __builtin_amdgcn_mfma_f32_16x16x32_bf16(
                    a[i], b[j], acc[i][j], 0, 0, 0);
    }

    const int crow = (lane >> 4) * 4;
    const int ccol = lane & 15;
    #pragma unroll
    for (int j = 0; j < 4; ++j) {
        int gcol = bn + wn + j * 16 + ccol;
        float bv = bias[gcol];
        #pragma unroll
        for (int i = 0; i < 4; ++i) {
            #pragma unroll
            for (int r = 0; r < 4; ++r) {
                int grow = bm + wm + i * 16 + crow + r;
                if (grow < M)
                    C[(size_t)grow * N + gcol] = acc[i][j][r] + bv;
            }
        }
    }
}

// ---------------------------------------------------------------------------
// Deformable sampling + aggregation (owner-computes + fma_mix + saddr),
// per-head v layout: v[((b*8+h)*LTOT + pixel)*32 + ch] fp16, 64 B per pixel.
// 4 threads per (b,q,h); thread st owns channels [st*8, st*8+8) AND level st.
// ---------------------------------------------------------------------------
__global__ __launch_bounds__(256, 6) void sampler4(
    const ushort* __restrict__ v,    // per-head fp16 table
    const float* __restrict__ qp,    // (BS*NQ, 768)
    const float* __restrict__ ref,   // (BS*NQ, 4, 2)
    ushort* __restrict__ agg)        // (BS*NQ, 256) bf16
{
    const int tid = threadIdx.x;
    const int g = blockIdx.x * 64 + (tid >> 2);   // (b*NQ+q)*8 + h
    const int st = tid & 3;                        // this lane owns level st
    const int h = g & 7;
    const int bq = g >> 3;
    const int b = blockIdx.x >> 9;                 // uniform: 512 blocks/batch

    // own level dims (LW = 160>>st; LH = {92,46,23,12}; LS prefix sums)
    const int Wl = 160 >> st;
    const int Hl = (st == 3) ? 12 : (92 >> st);
    const int Sl = (st == 0) ? 0 : (st == 1) ? 14720 : (st == 2) ? 18400 : 19320;

    // own level's 8 points -> pre-scaled pixel coords
    float px[8], py[8];
    {
        const float* offp = qp + (size_t)bq * 768 + h * 64 + st * 16;
        float o[16];
        #pragma unroll
        for (int i = 0; i < 4; ++i)
            *(float4*)&o[i * 4] = *(const float4*)(offp + i * 4);
        float2 rf = *(const float2*)(ref + (size_t)bq * 8 + st * 2);
        const float fW = (float)Wl, fH = (float)Hl;
        #pragma unroll
        for (int i = 0; i < 8; ++i) {
            px[i] = fmaf(rf.x, fW, o[2 * i]) - 0.5f;
            py[i] = fmaf(rf.y, fH, o[2 * i + 1]) - 0.5f;
        }
    }

    // fused softmax over 32 logits (8 per lane = own level, width-4 group)
    float a8[8];
    {
        const float* lp = qp + (size_t)bq * 768 + 512 + h * 32 + st * 8;
        *(float4*)&a8[0] = *(const float4*)(lp);
        *(float4*)&a8[4] = *(const float4*)(lp + 4);
        float m = a8[0];
        #pragma unroll
        for (int i = 1; i < 8; ++i) m = fmaxf(m, a8[i]);
        m = fmaxf(m, __shfl_xor(m, 1, 4));
        m = fmaxf(m, __shfl_xor(m, 2, 4));
        float s = 0.f;
        #pragma unroll
        for (int i = 0; i < 8; ++i) { a8[i] = __expf(a8[i] - m); s += a8[i]; }
        s += __shfl_xor(s, 1, 4);
        s += __shfl_xor(s, 2, 4);
        float inv = 1.f / s;
        #pragma unroll
        for (int i = 0; i < 8; ++i) a8[i] *= inv;
    }

    // SGPR-uniform batch base; per-lane (head, channel-slice) byte offset
    const char* vb = (const char*)v + (size_t)b * (NH * LTOT * 64);
    const uint32_t hoff = (uint32_t)(h * (LTOT * 64) + st * 16);

    float acc[8] = {0.f, 0.f, 0.f, 0.f, 0.f, 0.f, 0.f, 0.f};

    #pragma unroll
    for (int idx = 0; idx < 8; ++idx) {
        // ---- owner math: bilinear weights + pixel byte-offsets, own point ----
        float px_ = px[idx], py_ = py[idx];
        float x0f = floorf(px_), y0f = floorf(py_);
        float wx = px_ - x0f, wy = py_ - y0f;
        int x0 = (int)x0f, y0 = (int)y0f;
        int x1 = x0 + 1, y1 = y0 + 1;
        float vx0 = ((uint32_t)x0 < (uint32_t)Wl) ? 1.f : 0.f;
        float vx1 = ((uint32_t)x1 < (uint32_t)Wl) ? 1.f : 0.f;
        float vy0 = ((uint32_t)y0 < (uint32_t)Hl) ? 1.f : 0.f;
        float vy1 = ((uint32_t)y1 < (uint32_t)Hl) ? 1.f : 0.f;
        int cx0 = min(max(x0, 0), Wl - 1);
        int cx1 = min(max(x1, 0), Wl - 1);
        int cy0 = min(max(y0, 0), Hl - 1);
        int cy1 = min(max(y1, 0), Hl - 1);
        float aw = a8[idx];
        float omx = 1.f - wx, omy = 1.f - wy;
        float omya = omy * aw, wya = wy * aw;
        float w00 = omx * omya * (vx0 * vy0);
        float w10 = wx  * omya * (vx1 * vy0);
        float w01 = omx * wya  * (vx0 * vy1);
        float w11 = wx  * wya  * (vx1 * vy1);
        int r0 = Sl + cy0 * Wl;
        int r1 = Sl + cy1 * Wl;
        uint32_t e00 = (uint32_t)(r0 + cx0) << 6;   // pixel * 64 bytes
        uint32_t e10 = (uint32_t)(r0 + cx1) << 6;
        uint32_t e01 = (uint32_t)(r1 + cx0) << 6;
        uint32_t e11 = (uint32_t)(r1 + cx1) << 6;

        // ---- consume all 4 levels' points (broadcast from lane L) ----
        #define ACCMIX(w_, c_) \
            fmx_lo(acc[0], w_, c_.x); fmx_hi(acc[1], w_, c_.x); \
            fmx_lo(acc[2], w_, c_.y); fmx_hi(acc[3], w_, c_.y); \
            fmx_lo(acc[4], w_, c_.z); fmx_hi(acc[5], w_, c_.z); \
            fmx_lo(acc[6], w_, c_.w); fmx_hi(acc[7], w_, c_.w);
        #define DO_LEVEL(L) { \
            float W00 = bcastf<L>(w00), W10 = bcastf<L>(w10); \
            float W01 = bcastf<L>(w01), W11 = bcastf<L>(w11); \
            uint32_t E00 = bcastu<L>(e00), E10 = bcastu<L>(e10); \
            uint32_t E01 = bcastu<L>(e01), E11 = bcastu<L>(e11); \
            uint4 c00 = *(const uint4*)(vb + (E00 + hoff)); \
            uint4 c10 = *(const uint4*)(vb + (E10 + hoff)); \
            uint4 c01 = *(const uint4*)(vb + (E01 + hoff)); \
            uint4 c11 = *(const uint4*)(vb + (E11 + hoff)); \
            ACCMIX(W00, c00); ACCMIX(W10, c10); \
            ACCMIX(W01, c01); ACCMIX(W11, c11); }
        DO_LEVEL(0)
        DO_LEVEL(1)
        DO_LEVEL(2)
        DO_LEVEL(3)
        #undef DO_LEVEL
        #undef ACCMIX
    }

    ushort8v r;
    #pragma unroll
    for (int i = 0; i < 8; ++i) r[i] = f2bf(acc[i]);
    *(ushort8v*)(agg + (size_t)bq * 256 + h * 32 + st * 8) = r;
}

// ---------------------------------------------------------------------------
// Launch
// ---------------------------------------------------------------------------
extern "C" void kernel_launch(void* const* d_in, const int* in_sizes, int n_in,
                              void* d_out, int out_size, void* d_ws, size_t ws_size,
                              hipStream_t stream) {
    const float* query  = (const float*)d_in[0];
    const float* value  = (const float*)d_in[1];
    const float* refpts = (const float*)d_in[2];
    const float* W_off  = (const float*)d_in[4];
    const float* b_off  = (const float*)d_in[5];
    const float* W_attn = (const float*)d_in[6];
    const float* b_attn = (const float*)d_in[7];
    const float* W_val  = (const float*)d_in[8];
    const float* b_val  = (const float*)d_in[9];
    const float* W_out  = (const float*)d_in[10];
    const float* b_out  = (const float*)d_in[11];
    float* out = (float*)d_out;

    char* ws = (char*)d_ws;
    // layout (bytes):
    ushort* v_bf   = (ushort*)(ws);                     // 6*8*19560*32 fp16 = 60,088,320
    ushort* q_bf   = (ushort*)(ws + 60096512ull);       // 24576x256 bf16 = 12,582,912
    float*  qp     = (float*) (ws + 72679424ull);       // 24576x768 f32  = 75,497,472
    ushort* agg_bf = (ushort*)(ws + 148176896ull);      // 24576x256 bf16 = 12,582,912
    ushort* Wvt    = (ushort*)(ws + 160759808ull);      // 131,072
    ushort* Wq     = (ushort*)(ws + 160890880ull);      // 768x256 bf16 = 393,216
    ushort* Wot    = (ushort*)(ws + 161284096ull);      // 131,072
    float*  bcat   = (float*) (ws + 161415168ull);      // 3,072

    // weight preprocessing
    cast_t<<<(256 * 256) / 256, 256, 0, stream>>>(W_val, Wvt, 256);
    cast_t<<<(256 * 512) / 256, 256, 0, stream>>>(W_off, Wq, 512);
    cast_t<<<(256 * 256) / 256, 256, 0, stream>>>(W_attn, Wq + 512 * 256, 256);
    cast_t<<<(256 * 256) / 256, 256, 0, stream>>>(W_out, Wot, 256);
    bias_concat<<<1, 768, 0, stream>>>(b_off, b_attn, bcat);
    cast_bf16<<<(ROWS_Q * EMB / 8) / 256, 256, 0, stream>>>(
        query, q_bf, ROWS_Q * EMB);

    // 1. v = value @ W_val + b_val -> fp16 per-head layout
    vgemm<<<ROWS_VP / 128, 512, 0, stream>>>(value, Wvt, b_val, v_bf);

    // 2. qp = query @ [W_off | W_attn] + [b_off | b_attn]  (N=768)
    gemm_bt<<<dim3(ROWS_Q / 128, 6), 256, 0, stream>>>(
        q_bf, Wq, bcat, qp, ROWS_Q, 768);

    // 3. sampling + softmax + aggregation -> bf16 agg
    sampler4<<<(ROWS_Q * NH) / 64, 256, 0, stream>>>(
        v_bf, qp, refpts, agg_bf);

    // 4. out = agg @ W_out + b_out (bf16 MFMA, fp32 out)
    gemm_bt<<<dim3(ROWS_Q / 128, 2), 256, 0, stream>>>(
        agg_bf, Wot, b_out, out, ROWS_Q, 256);
}

// Round 4
// 446.719 us; speedup vs baseline: 1.1712x; 1.1712x over previous
//
#include <hip/hip_runtime.h>
#include <hip/hip_fp16.h>
#include <stdint.h>

// Problem constants
#define BS 6
#define NQ 4096
#define NH 8
#define EMB 256
#define LTOT 19560
#define ROWS_V 117360
#define ROWS_VP 117376          // padded to 917*128
#define ROWS_Q 24576            // 192*128

typedef __attribute__((ext_vector_type(8))) short bf16x8;
typedef __attribute__((ext_vector_type(4))) float floatx4;
typedef __attribute__((ext_vector_type(8))) unsigned short ushort8v;

__device__ __forceinline__ ushort f2bf(float f) {
    union { float f; uint32_t i; } c; c.f = f;
    uint32_t r = c.i + 0x7FFFu + ((c.i >> 16) & 1u);   // round-to-nearest-even
    return (ushort)(r >> 16);
}
__device__ __forceinline__ ushort f2h(float f) {
    __half h = __float2half(f);                        // RTE
    union { __half h; ushort u; } c; c.h = h; return c.u;
}

__device__ __forceinline__ void gll16(const ushort* g, ushort* l) {
    __builtin_amdgcn_global_load_lds(
        (const __attribute__((address_space(1))) void*)g,
        (__attribute__((address_space(3))) void*)l, 16, 0, 0);
}

// compile-time broadcast of lane L (within each 4-lane group) via ds_swizzle
// BitMode offset: [14:10]=xor [9:5]=or [4:0]=and ; src = ((lane&0x1C)|L)
template<int L>
__device__ __forceinline__ float bcastf(float x) {
    return __int_as_float(
        __builtin_amdgcn_ds_swizzle(__float_as_int(x), 0x1C | (L << 5)));
}
template<int L>
__device__ __forceinline__ uint32_t bcastu(uint32_t x) {
    return (uint32_t)__builtin_amdgcn_ds_swizzle((int)x, 0x1C | (L << 5));
}

// gfx950 mixed-precision FMA: acc = f32(w) * f16half(u) + acc
__device__ __forceinline__ void fmx_lo(float& acc, float w, uint32_t u) {
    asm("v_fma_mix_f32 %0, %1, %2, %0 op_sel:[0,0,0] op_sel_hi:[0,1,0]"
        : "+v"(acc) : "v"(w), "v"(u));
}
__device__ __forceinline__ void fmx_hi(float& acc, float w, uint32_t u) {
    asm("v_fma_mix_f32 %0, %1, %2, %0 op_sel:[0,1,0] op_sel_hi:[0,1,0]"
        : "+v"(acc) : "v"(w), "v"(u));
}

// ---------------------------------------------------------------------------
// fp32 -> bf16 cast (row-contiguous), 8 elems/thread
// ---------------------------------------------------------------------------
__global__ __launch_bounds__(256) void cast_bf16(
    const float* __restrict__ in, ushort* __restrict__ out, int n)
{
    int i = (blockIdx.x * 256 + threadIdx.x) * 8;
    if (i >= n) return;
    float4 f0 = *(const float4*)(in + i);
    float4 f1 = *(const float4*)(in + i + 4);
    ushort8v r;
    r[0] = f2bf(f0.x); r[1] = f2bf(f0.y); r[2] = f2bf(f0.z); r[3] = f2bf(f0.w);
    r[4] = f2bf(f1.x); r[5] = f2bf(f1.y); r[6] = f2bf(f1.z); r[7] = f2bf(f1.w);
    *(ushort8v*)(out + i) = r;
}

// ---------------------------------------------------------------------------
// W (K=256 x N) fp32  ->  Wt (N x 256) bf16   (tiny matrices)
// ---------------------------------------------------------------------------
__global__ __launch_bounds__(256) void cast_t(
    const float* __restrict__ W, ushort* __restrict__ Wt, int N_)
{
    int id = blockIdx.x * 256 + threadIdx.x;
    if (id >= 256 * N_) return;
    int n = id >> 8;         // / 256 (K = 256)
    int k = id & 255;
    Wt[id] = f2bf(W[(size_t)k * N_ + n]);
}

__global__ __launch_bounds__(768) void bias_concat(
    const float* __restrict__ b_off, const float* __restrict__ b_attn,
    float* __restrict__ bcat)
{
    int i = threadIdx.x;
    bcat[i] = (i < 512) ? b_off[i] : b_attn[i - 512];
}

// ---------------------------------------------------------------------------
// Fused value GEMM: v = value(fp32) @ Wvt^T + b_val -> fp16 (sampler input),
// row-contiguous (pixel, 256ch) layout.
// Block: 512 threads = 8 waves (2x4), tile 128(M) x 256(N=full), BK=32.
// ---------------------------------------------------------------------------
__global__ __launch_bounds__(512) void vgemm(
    const float* __restrict__ A,     // ROWS_V x 256 fp32
    const ushort* __restrict__ Bt,   // 256 x 256 bf16
    const float* __restrict__ bias,  // 256
    ushort* __restrict__ C)          // ROWS_VP x 256 fp16
{
    constexpr int K = 256, N = 256, M = ROWS_V;
    __shared__ ushort As[128 * 32];
    __shared__ ushort Bs[256 * 32];

    const int t = threadIdx.x;
    const int w = t >> 6;
    const int lane = t & 63;
    const int bm = blockIdx.x * 128;
    const int wm = (w >> 2) * 64;
    const int wn = (w & 3) * 64;

    // A staging: thread t -> row t>>2 (0..127), cols (t&3)*8 .. +8
    const int arow = t >> 2;
    const int acol = (t & 3) * 8;
    const bool rowok = (bm + arow) < M;
    const float* Ap = A + (size_t)(bm + arow) * K + acol;
    ushort* Asw = &As[arow * 32 + acol];

    // B staging: wave w stages rows [32w, 32w+32) in two 16-row chunks
    const int srow = lane >> 2;
    const int scol = (lane & 3) * 8;
    const ushort* Bg0 = Bt + (size_t)(w * 32 + srow) * K + scol;
    const ushort* Bg1 = Bt + (size_t)(w * 32 + 16 + srow) * K + scol;
    ushort* Bl0 = &Bs[(w * 32) * 32];
    ushort* Bl1 = &Bs[(w * 32 + 16) * 32];

    const ushort* apt = &As[(wm + (lane & 15)) * 32 + (lane >> 4) * 8];
    const ushort* bpt = &Bs[(wn + (lane & 15)) * 32 + (lane >> 4) * 8];

    floatx4 acc[4][4] = {};

    for (int kt = 0; kt < K; kt += 32) {
        float4 f0, f1;
        if (rowok) {
            f0 = *(const float4*)(Ap + kt);
            f1 = *(const float4*)(Ap + kt + 4);
        } else {
            f0 = make_float4(0.f, 0.f, 0.f, 0.f);
            f1 = f0;
        }
        __syncthreads();   // previous iter's fragment reads done
        gll16(Bg0 + kt, Bl0);
        gll16(Bg1 + kt, Bl1);
        ushort8v u;
        u[0] = f2bf(f0.x); u[1] = f2bf(f0.y); u[2] = f2bf(f0.z); u[3] = f2bf(f0.w);
        u[4] = f2bf(f1.x); u[5] = f2bf(f1.y); u[6] = f2bf(f1.z); u[7] = f2bf(f1.w);
        *(ushort8v*)Asw = u;
        __syncthreads();   // staging visible (drains vmcnt + lgkmcnt)

        bf16x8 a[4], b[4];
        #pragma unroll
        for (int i = 0; i < 4; ++i) {
            a[i] = *(const bf16x8*)(apt + i * 16 * 32);
            b[i] = *(const bf16x8*)(bpt + i * 16 * 32);
        }
        #pragma unroll
        for (int i = 0; i < 4; ++i)
            #pragma unroll
            for (int j = 0; j < 4; ++j)
                acc[i][j] = __builtin_amdgcn_mfma_f32_16x16x32_bf16(
                    a[i], b[j], acc[i][j], 0, 0, 0);
    }

    const int crow = (lane >> 4) * 4;
    const int ccol = lane & 15;
    #pragma unroll
    for (int j = 0; j < 4; ++j) {
        int gcol = wn + j * 16 + ccol;
        float bv = bias[gcol];
        #pragma unroll
        for (int i = 0; i < 4; ++i) {
            #pragma unroll
            for (int r = 0; r < 4; ++r) {
                int grow = bm + wm + i * 16 + crow + r;
                if (grow < M)
                    C[(size_t)grow * N + gcol] = f2h(acc[i][j][r] + bv);
            }
        }
    }
}

// ---------------------------------------------------------------------------
// bf16 MFMA GEMM (m97 structure): C[M,N] = A[M,256] @ Bt[N,256]^T + bias
// fp32 output. 128x128 tile, 256 threads = 4 waves.
// ---------------------------------------------------------------------------
__global__ __launch_bounds__(256) void gemm_bt(
    const ushort* __restrict__ A,    // Mpad x 256 bf16
    const ushort* __restrict__ Bt,   // N x 256 bf16
    const float* __restrict__ bias,  // N
    float* __restrict__ C, int M, int N)
{
    constexpr int K = 256;
    __shared__ ushort As[128 * 32];
    __shared__ ushort Bs[128 * 32];

    const int t = threadIdx.x;
    const int w = t >> 6;
    const int lane = t & 63;
    const int bm = blockIdx.x * 128;
    const int bn = blockIdx.y * 128;
    const int wm = (w >> 1) * 64;
    const int wn = (w & 1) * 64;

    floatx4 acc[4][4] = {};

    const int srow = lane >> 2;
    const int scol = (lane & 3) * 8;
    const ushort* Ag0 = A + (size_t)(bm + (w * 2 + 0) * 16 + srow) * K + scol;
    const ushort* Ag1 = A + (size_t)(bm + (w * 2 + 1) * 16 + srow) * K + scol;
    const ushort* Bg0 = Bt + (size_t)(bn + (w * 2 + 0) * 16 + srow) * K + scol;
    const ushort* Bg1 = Bt + (size_t)(bn + (w * 2 + 1) * 16 + srow) * K + scol;
    ushort* Al0 = &As[(w * 2 + 0) * 512];
    ushort* Al1 = &As[(w * 2 + 1) * 512];
    ushort* Bl0 = &Bs[(w * 2 + 0) * 512];
    ushort* Bl1 = &Bs[(w * 2 + 1) * 512];

    const ushort* apt = &As[(wm + (lane & 15)) * 32 + (lane >> 4) * 8];
    const ushort* bpt = &Bs[(wn + (lane & 15)) * 32 + (lane >> 4) * 8];

    for (int kt = 0; kt < K; kt += 32) {
        __syncthreads();
        gll16(Ag0 + kt, Al0);
        gll16(Ag1 + kt, Al1);
        gll16(Bg0 + kt, Bl0);
        gll16(Bg1 + kt, Bl1);
        __syncthreads();

        bf16x8 a[4], b[4];
        #pragma unroll
        for (int i = 0; i < 4; ++i) {
            a[i] = *(const bf16x8*)(apt + i * 16 * 32);
            b[i] = *(const bf16x8*)(bpt + i * 16 * 32);
        }
        #pragma unroll
        for (int i = 0; i < 4; ++i)
            #pragma unroll
            for (int j = 0; j < 4; ++j)
                acc[i][j] = __builtin_amdgcn_mfma_f32_16x16x32_bf16(
                    a[i], b[j], acc[i][j], 0, 0, 0);
    }

    const int crow = (lane >> 4) * 4;
    const int ccol = lane & 15;
    #pragma unroll
    for (int j = 0; j < 4; ++j) {
        int gcol = bn + wn + j * 16 + ccol;
        float bv = bias[gcol];
        #pragma unroll
        for (int i = 0; i < 4; ++i) {
            #pragma unroll
            for (int r = 0; r < 4; ++r) {
                int grow = bm + wm + i * 16 + crow + r;
                if (grow < M)
                    C[(size_t)grow * N + gcol] = acc[i][j][r] + bv;
            }
        }
    }
}

// ---------------------------------------------------------------------------
// Deformable sampling + aggregation (owner-computes + fma_mix + saddr),
// (pixel, 256ch) fp16 v layout — cross-head line sharing within a block.
// 48 KB LDS ballast caps residency at 3 blocks/CU (12 waves) to keep the
// concurrent gather hot-set inside L1/L2 (R2's 24-wave run thrashed: 633 MB).
// 4 threads per (b,q,h); thread st owns channels [st*8, st*8+8) AND level st.
// ---------------------------------------------------------------------------
__global__ __launch_bounds__(256) void sampler4(
    const ushort* __restrict__ v,    // (BS, LTOT, 256) fp16
    const float* __restrict__ qp,    // (BS*NQ, 768)
    const float* __restrict__ ref,   // (BS*NQ, 4, 2)
    ushort* __restrict__ agg)        // (BS*NQ, 256) bf16
{
    __shared__ char ballast[49152];          // occupancy cap: 3 blocks/CU
    if (blockIdx.x > 0x7FFFFFF0u) {          // never true; unprovable -> kept
        ballast[threadIdx.x] = (char)threadIdx.x;
        agg[0] = (ushort)ballast[(threadIdx.x * 37) & 4095];
    }

    const int tid = threadIdx.x;
    const int g = blockIdx.x * 64 + (tid >> 2);   // (b*NQ+q)*8 + h
    const int st = tid & 3;                        // this lane owns level st
    const int h = g & 7;
    const int bq = g >> 3;
    const int b = blockIdx.x >> 9;                 // uniform: 512 blocks/batch

    // own level dims (LW = 160>>st; LH = {92,46,23,12}; LS prefix sums)
    const int Wl = 160 >> st;
    const int Hl = (st == 3) ? 12 : (92 >> st);
    const int Sl = (st == 0) ? 0 : (st == 1) ? 14720 : (st == 2) ? 18400 : 19320;

    // own level's 8 points -> pre-scaled pixel coords
    float px[8], py[8];
    {
        const float* offp = qp + (size_t)bq * 768 + h * 64 + st * 16;
        float o[16];
        #pragma unroll
        for (int i = 0; i < 4; ++i)
            *(float4*)&o[i * 4] = *(const float4*)(offp + i * 4);
        float2 rf = *(const float2*)(ref + (size_t)bq * 8 + st * 2);
        const float fW = (float)Wl, fH = (float)Hl;
        #pragma unroll
        for (int i = 0; i < 8; ++i) {
            px[i] = fmaf(rf.x, fW, o[2 * i]) - 0.5f;
            py[i] = fmaf(rf.y, fH, o[2 * i + 1]) - 0.5f;
        }
    }

    // fused softmax over 32 logits (8 per lane = own level, width-4 group)
    float a8[8];
    {
        const float* lp = qp + (size_t)bq * 768 + 512 + h * 32 + st * 8;
        *(float4*)&a8[0] = *(const float4*)(lp);
        *(float4*)&a8[4] = *(const float4*)(lp + 4);
        float m = a8[0];
        #pragma unroll
        for (int i = 1; i < 8; ++i) m = fmaxf(m, a8[i]);
        m = fmaxf(m, __shfl_xor(m, 1, 4));
        m = fmaxf(m, __shfl_xor(m, 2, 4));
        float s = 0.f;
        #pragma unroll
        for (int i = 0; i < 8; ++i) { a8[i] = __expf(a8[i] - m); s += a8[i]; }
        s += __shfl_xor(s, 1, 4);
        s += __shfl_xor(s, 2, 4);
        float inv = 1.f / s;
        #pragma unroll
        for (int i = 0; i < 8; ++i) a8[i] *= inv;
    }

    // SGPR-uniform batch base; per-lane (head, channel-slice) byte offset
    const char* vb = (const char*)(v + (size_t)b * (LTOT * EMB));
    const uint32_t coffB = (uint32_t)(h * 64 + st * 16);   // bytes

    float acc[8] = {0.f, 0.f, 0.f, 0.f, 0.f, 0.f, 0.f, 0.f};

    #pragma unroll
    for (int idx = 0; idx < 8; ++idx) {
        // ---- owner math: bilinear weights + row byte-offsets, own point ----
        float px_ = px[idx], py_ = py[idx];
        float x0f = floorf(px_), y0f = floorf(py_);
        float wx = px_ - x0f, wy = py_ - y0f;
        int x0 = (int)x0f, y0 = (int)y0f;
        int x1 = x0 + 1, y1 = y0 + 1;
        float vx0 = ((uint32_t)x0 < (uint32_t)Wl) ? 1.f : 0.f;
        float vx1 = ((uint32_t)x1 < (uint32_t)Wl) ? 1.f : 0.f;
        float vy0 = ((uint32_t)y0 < (uint32_t)Hl) ? 1.f : 0.f;
        float vy1 = ((uint32_t)y1 < (uint32_t)Hl) ? 1.f : 0.f;
        int cx0 = min(max(x0, 0), Wl - 1);
        int cx1 = min(max(x1, 0), Wl - 1);
        int cy0 = min(max(y0, 0), Hl - 1);
        int cy1 = min(max(y1, 0), Hl - 1);
        float aw = a8[idx];
        float omx = 1.f - wx, omy = 1.f - wy;
        float omya = omy * aw, wya = wy * aw;
        float w00 = omx * omya * (vx0 * vy0);
        float w10 = wx  * omya * (vx1 * vy0);
        float w01 = omx * wya  * (vx0 * vy1);
        float w11 = wx  * wya  * (vx1 * vy1);
        int r0 = Sl + cy0 * Wl;
        int r1 = Sl + cy1 * Wl;
        uint32_t e00 = (uint32_t)(r0 + cx0) << 9;   // pixel-row * 512 bytes
        uint32_t e10 = (uint32_t)(r0 + cx1) << 9;
        uint32_t e01 = (uint32_t)(r1 + cx0) << 9;
        uint32_t e11 = (uint32_t)(r1 + cx1) << 9;

        // ---- consume all 4 levels' points (broadcast from lane L) ----
        #define ACCMIX(w_, c_) \
            fmx_lo(acc[0], w_, c_.x); fmx_hi(acc[1], w_, c_.x); \
            fmx_lo(acc[2], w_, c_.y); fmx_hi(acc[3], w_, c_.y); \
            fmx_lo(acc[4], w_, c_.z); fmx_hi(acc[5], w_, c_.z); \
            fmx_lo(acc[6], w_, c_.w); fmx_hi(acc[7], w_, c_.w);
        #define DO_LEVEL(L) { \
            float W00 = bcastf<L>(w00), W10 = bcastf<L>(w10); \
            float W01 = bcastf<L>(w01), W11 = bcastf<L>(w11); \
            uint32_t E00 = bcastu<L>(e00), E10 = bcastu<L>(e10); \
            uint32_t E01 = bcastu<L>(e01), E11 = bcastu<L>(e11); \
            uint4 c00 = *(const uint4*)(vb + (E00 + coffB)); \
            uint4 c10 = *(const uint4*)(vb + (E10 + coffB)); \
            uint4 c01 = *(const uint4*)(vb + (E01 + coffB)); \
            uint4 c11 = *(const uint4*)(vb + (E11 + coffB)); \
            ACCMIX(W00, c00); ACCMIX(W10, c10); \
            ACCMIX(W01, c01); ACCMIX(W11, c11); }
        DO_LEVEL(0)
        DO_LEVEL(1)
        DO_LEVEL(2)
        DO_LEVEL(3)
        #undef DO_LEVEL
        #undef ACCMIX
    }

    ushort8v r;
    #pragma unroll
    for (int i = 0; i < 8; ++i) r[i] = f2bf(acc[i]);
    *(ushort8v*)(agg + (size_t)bq * 256 + h * 32 + st * 8) = r;
}

// ---------------------------------------------------------------------------
// Launch
// ---------------------------------------------------------------------------
extern "C" void kernel_launch(void* const* d_in, const int* in_sizes, int n_in,
                              void* d_out, int out_size, void* d_ws, size_t ws_size,
                              hipStream_t stream) {
    const float* query  = (const float*)d_in[0];
    const float* value  = (const float*)d_in[1];
    const float* refpts = (const float*)d_in[2];
    const float* W_off  = (const float*)d_in[4];
    const float* b_off  = (const float*)d_in[5];
    const float* W_attn = (const float*)d_in[6];
    const float* b_attn = (const float*)d_in[7];
    const float* W_val  = (const float*)d_in[8];
    const float* b_val  = (const float*)d_in[9];
    const float* W_out  = (const float*)d_in[10];
    const float* b_out  = (const float*)d_in[11];
    float* out = (float*)d_out;

    char* ws = (char*)d_ws;
    // layout (bytes):
    ushort* v_bf   = (ushort*)(ws);                     // 117376x256 fp16 = 60,096,512
    ushort* q_bf   = (ushort*)(ws + 60096512ull);       // 24576x256 bf16 = 12,582,912
    float*  qp     = (float*) (ws + 72679424ull);       // 24576x768 f32  = 75,497,472
    ushort* agg_bf = (ushort*)(ws + 148176896ull);      // 24576x256 bf16 = 12,582,912
    ushort* Wvt    = (ushort*)(ws + 160759808ull);      // 131,072
    ushort* Wq     = (ushort*)(ws + 160890880ull);      // 768x256 bf16 = 393,216
    ushort* Wot    = (ushort*)(ws + 161284096ull);      // 131,072
    float*  bcat   = (float*) (ws + 161415168ull);      // 3,072

    // weight preprocessing
    cast_t<<<(256 * 256) / 256, 256, 0, stream>>>(W_val, Wvt, 256);
    cast_t<<<(256 * 512) / 256, 256, 0, stream>>>(W_off, Wq, 512);
    cast_t<<<(256 * 256) / 256, 256, 0, stream>>>(W_attn, Wq + 512 * 256, 256);
    cast_t<<<(256 * 256) / 256, 256, 0, stream>>>(W_out, Wot, 256);
    bias_concat<<<1, 768, 0, stream>>>(b_off, b_attn, bcat);
    cast_bf16<<<(ROWS_Q * EMB / 8) / 256, 256, 0, stream>>>(
        query, q_bf, ROWS_Q * EMB);

    // 1. v = value @ W_val + b_val -> fp16 (fused fp32 read + cast)
    vgemm<<<ROWS_VP / 128, 512, 0, stream>>>(value, Wvt, b_val, v_bf);

    // 2. qp = query @ [W_off | W_attn] + [b_off | b_attn]  (N=768)
    gemm_bt<<<dim3(ROWS_Q / 128, 6), 256, 0, stream>>>(
        q_bf, Wq, bcat, qp, ROWS_Q, 768);

    // 3. sampling + softmax + aggregation -> bf16 agg
    sampler4<<<(ROWS_Q * NH) / 64, 256, 0, stream>>>(
        v_bf, qp, refpts, agg_bf);

    // 4. out = agg @ W_out + b_out (bf16 MFMA, fp32 out)
    gemm_bt<<<dim3(ROWS_Q / 128, 2), 256, 0, stream>>>(
        agg_bf, Wot, b_out, out, ROWS_Q, 256);
}

// Round 5
// 423.215 us; speedup vs baseline: 1.2363x; 1.0555x over previous
//
#include <hip/hip_runtime.h>
#include <hip/hip_fp16.h>
#include <stdint.h>

// Problem constants
#define BS 6
#define NQ 4096
#define NH 8
#define EMB 256
#define LTOT 19560
#define ROWS_V 117360
#define ROWS_VP 117376          // padded to 917*128
#define ROWS_Q 24576            // 192*128

typedef __attribute__((ext_vector_type(8))) short bf16x8;
typedef __attribute__((ext_vector_type(4))) float floatx4;
typedef __attribute__((ext_vector_type(8))) unsigned short ushort8v;

__device__ __forceinline__ ushort f2bf(float f) {
    union { float f; uint32_t i; } c; c.f = f;
    uint32_t r = c.i + 0x7FFFu + ((c.i >> 16) & 1u);   // round-to-nearest-even
    return (ushort)(r >> 16);
}
__device__ __forceinline__ ushort f2h(float f) {
    __half h = __float2half(f);                        // RTE
    union { __half h; ushort u; } c; c.h = h; return c.u;
}
__device__ __forceinline__ float h2f(ushort u) {
    union { ushort u; __half h; } c; c.u = u; return __half2float(c.h);
}

__device__ __forceinline__ void gll16(const ushort* g, ushort* l) {
    __builtin_amdgcn_global_load_lds(
        (const __attribute__((address_space(1))) void*)g,
        (__attribute__((address_space(3))) void*)l, 16, 0, 0);
}

// compile-time broadcast of lane L (within each 4-lane group) via ds_swizzle
template<int L>
__device__ __forceinline__ float bcastf(float x) {
    return __int_as_float(
        __builtin_amdgcn_ds_swizzle(__float_as_int(x), 0x1C | (L << 5)));
}
template<int L>
__device__ __forceinline__ uint32_t bcastu(uint32_t x) {
    return (uint32_t)__builtin_amdgcn_ds_swizzle((int)x, 0x1C | (L << 5));
}

// gfx950 mixed-precision FMA: acc = f32(w) * f16half(u) + acc
__device__ __forceinline__ void fmx_lo(float& acc, float w, uint32_t u) {
    asm("v_fma_mix_f32 %0, %1, %2, %0 op_sel:[0,0,0] op_sel_hi:[0,1,0]"
        : "+v"(acc) : "v"(w), "v"(u));
}
__device__ __forceinline__ void fmx_hi(float& acc, float w, uint32_t u) {
    asm("v_fma_mix_f32 %0, %1, %2, %0 op_sel:[0,1,0] op_sel_hi:[0,1,0]"
        : "+v"(acc) : "v"(w), "v"(u));
}

// ---------------------------------------------------------------------------
// Fused weight prep: all 4 transposed-cast weights + bias concat, 1 kernel.
// id ranges: [0,64K) Wvt | [64K,192K) Wq(off) | [192K,256K) Wq(attn)
//            [256K,320K) Wot | [320K,320K+768) bcat
// ---------------------------------------------------------------------------
__global__ __launch_bounds__(256) void prep(
    const float* __restrict__ W_val, const float* __restrict__ W_off,
    const float* __restrict__ W_attn, const float* __restrict__ W_out,
    const float* __restrict__ b_off, const float* __restrict__ b_attn,
    ushort* __restrict__ Wvt, ushort* __restrict__ Wq,
    ushort* __restrict__ Wot, float* __restrict__ bcat)
{
    int id = blockIdx.x * 256 + threadIdx.x;
    if (id < 65536) {
        int n = id >> 8, k = id & 255;
        Wvt[id] = f2bf(W_val[k * 256 + n]);
        return;
    }
    id -= 65536;
    if (id < 131072) {
        int n = id >> 8, k = id & 255;
        Wq[id] = f2bf(W_off[k * 512 + n]);
        return;
    }
    id -= 131072;
    if (id < 65536) {
        int n = id >> 8, k = id & 255;
        Wq[131072 + id] = f2bf(W_attn[k * 256 + n]);
        return;
    }
    id -= 65536;
    if (id < 65536) {
        int n = id >> 8, k = id & 255;
        Wot[id] = f2bf(W_out[k * 256 + n]);
        return;
    }
    id -= 65536;
    if (id < 768) bcat[id] = (id < 512) ? b_off[id] : b_attn[id - 512];
}

// ---------------------------------------------------------------------------
// Fused value GEMM: v = value(fp32) @ Wvt^T + b_val -> fp16 (sampler input),
// row-contiguous (pixel, 256ch) layout.
// Block: 512 threads = 8 waves (2x4), tile 128(M) x 256(N=full), BK=32.
// ---------------------------------------------------------------------------
__global__ __launch_bounds__(512) void vgemm(
    const float* __restrict__ A,     // ROWS_V x 256 fp32
    const ushort* __restrict__ Bt,   // 256 x 256 bf16
    const float* __restrict__ bias,  // 256
    ushort* __restrict__ C)          // ROWS_VP x 256 fp16
{
    constexpr int K = 256, N = 256, M = ROWS_V;
    __shared__ ushort As[128 * 32];
    __shared__ ushort Bs[256 * 32];

    const int t = threadIdx.x;
    const int w = t >> 6;
    const int lane = t & 63;
    const int bm = blockIdx.x * 128;
    const int wm = (w >> 2) * 64;
    const int wn = (w & 3) * 64;

    const int arow = t >> 2;
    const int acol = (t & 3) * 8;
    const bool rowok = (bm + arow) < M;
    const float* Ap = A + (size_t)(bm + arow) * K + acol;
    ushort* Asw = &As[arow * 32 + acol];

    const int srow = lane >> 2;
    const int scol = (lane & 3) * 8;
    const ushort* Bg0 = Bt + (size_t)(w * 32 + srow) * K + scol;
    const ushort* Bg1 = Bt + (size_t)(w * 32 + 16 + srow) * K + scol;
    ushort* Bl0 = &Bs[(w * 32) * 32];
    ushort* Bl1 = &Bs[(w * 32 + 16) * 32];

    const ushort* apt = &As[(wm + (lane & 15)) * 32 + (lane >> 4) * 8];
    const ushort* bpt = &Bs[(wn + (lane & 15)) * 32 + (lane >> 4) * 8];

    floatx4 acc[4][4] = {};

    for (int kt = 0; kt < K; kt += 32) {
        float4 f0, f1;
        if (rowok) {
            f0 = *(const float4*)(Ap + kt);
            f1 = *(const float4*)(Ap + kt + 4);
        } else {
            f0 = make_float4(0.f, 0.f, 0.f, 0.f);
            f1 = f0;
        }
        __syncthreads();   // previous iter's fragment reads done
        gll16(Bg0 + kt, Bl0);
        gll16(Bg1 + kt, Bl1);
        ushort8v u;
        u[0] = f2bf(f0.x); u[1] = f2bf(f0.y); u[2] = f2bf(f0.z); u[3] = f2bf(f0.w);
        u[4] = f2bf(f1.x); u[5] = f2bf(f1.y); u[6] = f2bf(f1.z); u[7] = f2bf(f1.w);
        *(ushort8v*)Asw = u;
        __syncthreads();   // staging visible (drains vmcnt + lgkmcnt)

        bf16x8 a[4], b[4];
        #pragma unroll
        for (int i = 0; i < 4; ++i) {
            a[i] = *(const bf16x8*)(apt + i * 16 * 32);
            b[i] = *(const bf16x8*)(bpt + i * 16 * 32);
        }
        #pragma unroll
        for (int i = 0; i < 4; ++i)
            #pragma unroll
            for (int j = 0; j < 4; ++j)
                acc[i][j] = __builtin_amdgcn_mfma_f32_16x16x32_bf16(
                    a[i], b[j], acc[i][j], 0, 0, 0);
    }

    const int crow = (lane >> 4) * 4;
    const int ccol = lane & 15;
    #pragma unroll
    for (int j = 0; j < 4; ++j) {
        int gcol = wn + j * 16 + ccol;
        float bv = bias[gcol];
        #pragma unroll
        for (int i = 0; i < 4; ++i) {
            #pragma unroll
            for (int r = 0; r < 4; ++r) {
                int grow = bm + wm + i * 16 + crow + r;
                if (grow < M)
                    C[(size_t)grow * N + gcol] = f2h(acc[i][j][r] + bv);
            }
        }
    }
}

// ---------------------------------------------------------------------------
// qp GEMM, fused query cast: qp = query(fp32) @ Wq^T + bcat -> f16
// 128x128 tile, 256 threads = 4 waves. A: fp32->reg->bf16->LDS. B: gll16.
// ---------------------------------------------------------------------------
__global__ __launch_bounds__(256) void qgemm(
    const float* __restrict__ A,     // ROWS_Q x 256 fp32 (query)
    const ushort* __restrict__ Bt,   // 768 x 256 bf16 (Wq)
    const float* __restrict__ bias,  // 768 (bcat)
    ushort* __restrict__ C)          // ROWS_Q x 768 f16 (qp)
{
    constexpr int K = 256, N = 768;
    __shared__ ushort As[128 * 32];
    __shared__ ushort Bs[128 * 32];

    const int t = threadIdx.x;
    const int w = t >> 6;
    const int lane = t & 63;
    const int bm = blockIdx.x * 128;
    const int bn = blockIdx.y * 128;
    const int wm = (w >> 1) * 64;
    const int wn = (w & 1) * 64;

    // A staging: thread t -> row t>>1 (0..127), cols (t&1)*16 .. +16
    const int arow = t >> 1;
    const int acol = (t & 1) * 16;
    const float* Ap = A + (size_t)(bm + arow) * K + acol;
    ushort* Asw = &As[arow * 32 + acol];

    // B staging: wave w stages rows [32w, 32w+32) in two 16-row chunks
    const int srow = lane >> 2;
    const int scol = (lane & 3) * 8;
    const ushort* Bg0 = Bt + (size_t)(bn + w * 32 + srow) * K + scol;
    const ushort* Bg1 = Bt + (size_t)(bn + w * 32 + 16 + srow) * K + scol;
    ushort* Bl0 = &Bs[(w * 32) * 32];
    ushort* Bl1 = &Bs[(w * 32 + 16) * 32];

    const ushort* apt = &As[(wm + (lane & 15)) * 32 + (lane >> 4) * 8];
    const ushort* bpt = &Bs[(wn + (lane & 15)) * 32 + (lane >> 4) * 8];

    floatx4 acc[4][4] = {};

    for (int kt = 0; kt < K; kt += 32) {
        float4 f0 = *(const float4*)(Ap + kt);
        float4 f1 = *(const float4*)(Ap + kt + 4);
        float4 f2 = *(const float4*)(Ap + kt + 8);
        float4 f3 = *(const float4*)(Ap + kt + 12);
        __syncthreads();   // previous iter's fragment reads done
        gll16(Bg0 + kt, Bl0);
        gll16(Bg1 + kt, Bl1);
        ushort8v u0, u1;
        u0[0] = f2bf(f0.x); u0[1] = f2bf(f0.y); u0[2] = f2bf(f0.z); u0[3] = f2bf(f0.w);
        u0[4] = f2bf(f1.x); u0[5] = f2bf(f1.y); u0[6] = f2bf(f1.z); u0[7] = f2bf(f1.w);
        u1[0] = f2bf(f2.x); u1[1] = f2bf(f2.y); u1[2] = f2bf(f2.z); u1[3] = f2bf(f2.w);
        u1[4] = f2bf(f3.x); u1[5] = f2bf(f3.y); u1[6] = f2bf(f3.z); u1[7] = f2bf(f3.w);
        *(ushort8v*)Asw = u0;
        *(ushort8v*)(Asw + 8) = u1;
        __syncthreads();   // staging visible

        bf16x8 a[4], b[4];
        #pragma unroll
        for (int i = 0; i < 4; ++i) {
            a[i] = *(const bf16x8*)(apt + i * 16 * 32);
            b[i] = *(const bf16x8*)(bpt + i * 16 * 32);
        }
        #pragma unroll
        for (int i = 0; i < 4; ++i)
            #pragma unroll
            for (int j = 0; j < 4; ++j)
                acc[i][j] = __builtin_amdgcn_mfma_f32_16x16x32_bf16(
                    a[i], b[j], acc[i][j], 0, 0, 0);
    }

    const int crow = (lane >> 4) * 4;
    const int ccol = lane & 15;
    #pragma unroll
    for (int j = 0; j < 4; ++j) {
        int gcol = bn + wn + j * 16 + ccol;
        float bv = bias[gcol];
        #pragma unroll
        for (int i = 0; i < 4; ++i) {
            int grow = bm + wm + i * 16 + crow;
            #pragma unroll
            for (int r = 0; r < 4; ++r)
                C[(size_t)(grow + r) * N + gcol] = f2h(acc[i][j][r] + bv);
        }
    }
}

// ---------------------------------------------------------------------------
// bf16 MFMA GEMM (m97 structure): C[M,N] = A[M,256] @ Bt[N,256]^T + bias
// fp32 output. 128x128 tile, 256 threads = 4 waves.  (out projection)
// ---------------------------------------------------------------------------
__global__ __launch_bounds__(256) void gemm_bt(
    const ushort* __restrict__ A,    // Mpad x 256 bf16
    const ushort* __restrict__ Bt,   // N x 256 bf16
    const float* __restrict__ bias,  // N
    float* __restrict__ C, int M, int N)
{
    constexpr int K = 256;
    __shared__ ushort As[128 * 32];
    __shared__ ushort Bs[128 * 32];

    const int t = threadIdx.x;
    const int w = t >> 6;
    const int lane = t & 63;
    const int bm = blockIdx.x * 128;
    const int bn = blockIdx.y * 128;
    const int wm = (w >> 1) * 64;
    const int wn = (w & 1) * 64;

    floatx4 acc[4][4] = {};

    const int srow = lane >> 2;
    const int scol = (lane & 3) * 8;
    const ushort* Ag0 = A + (size_t)(bm + (w * 2 + 0) * 16 + srow) * K + scol;
    const ushort* Ag1 = A + (size_t)(bm + (w * 2 + 1) * 16 + srow) * K + scol;
    const ushort* Bg0 = Bt + (size_t)(bn + (w * 2 + 0) * 16 + srow) * K + scol;
    const ushort* Bg1 = Bt + (size_t)(bn + (w * 2 + 1) * 16 + srow) * K + scol;
    ushort* Al0 = &As[(w * 2 + 0) * 512];
    ushort* Al1 = &As[(w * 2 + 1) * 512];
    ushort* Bl0 = &Bs[(w * 2 + 0) * 512];
    ushort* Bl1 = &Bs[(w * 2 + 1) * 512];

    const ushort* apt = &As[(wm + (lane & 15)) * 32 + (lane >> 4) * 8];
    const ushort* bpt = &Bs[(wn + (lane & 15)) * 32 + (lane >> 4) * 8];

    for (int kt = 0; kt < K; kt += 32) {
        __syncthreads();
        gll16(Ag0 + kt, Al0);
        gll16(Ag1 + kt, Al1);
        gll16(Bg0 + kt, Bl0);
        gll16(Bg1 + kt, Bl1);
        __syncthreads();

        bf16x8 a[4], b[4];
        #pragma unroll
        for (int i = 0; i < 4; ++i) {
            a[i] = *(const bf16x8*)(apt + i * 16 * 32);
            b[i] = *(const bf16x8*)(bpt + i * 16 * 32);
        }
        #pragma unroll
        for (int i = 0; i < 4; ++i)
            #pragma unroll
            for (int j = 0; j < 4; ++j)
                acc[i][j] = __builtin_amdgcn_mfma_f32_16x16x32_bf16(
                    a[i], b[j], acc[i][j], 0, 0, 0);
    }

    const int crow = (lane >> 4) * 4;
    const int ccol = lane & 15;
    #pragma unroll
    for (int j = 0; j < 4; ++j) {
        int gcol = bn + wn + j * 16 + ccol;
        float bv = bias[gcol];
        #pragma unroll
        for (int i = 0; i < 4; ++i) {
            #pragma unroll
            for (int r = 0; r < 4; ++r) {
                int grow = bm + wm + i * 16 + crow + r;
                if (grow < M)
                    C[(size_t)grow * N + gcol] = acc[i][j][r] + bv;
            }
        }
    }
}

// ---------------------------------------------------------------------------
// Deformable sampling + aggregation (owner-computes + fma_mix + saddr),
// (pixel, 256ch) fp16 v layout — cross-head line sharing within a block.
// 48 KB LDS ballast caps residency at 3 blocks/CU (12 waves): keeps the
// concurrent gather hot-set inside L1/L2 (24-wave run thrashed: 633 MB).
// qp is f16 here (1536 B/row): [0:512) offsets, [512:768) logits.
// ---------------------------------------------------------------------------
__global__ __launch_bounds__(256) void sampler4(
    const ushort* __restrict__ v,    // (BS, LTOT, 256) fp16
    const ushort* __restrict__ qp,   // (BS*NQ, 768) f16
    const float* __restrict__ ref,   // (BS*NQ, 4, 2)
    ushort* __restrict__ agg)        // (BS*NQ, 256) bf16
{
    __shared__ char ballast[49152];          // occupancy cap: 3 blocks/CU
    if (blockIdx.x > 0x7FFFFFF0u) {          // never true; unprovable -> kept
        ballast[threadIdx.x] = (char)threadIdx.x;
        agg[0] = (ushort)ballast[(threadIdx.x * 37) & 4095];
    }

    const int tid = threadIdx.x;
    const int g = blockIdx.x * 64 + (tid >> 2);   // (b*NQ+q)*8 + h
    const int st = tid & 3;                        // this lane owns level st
    const int h = g & 7;
    const int bq = g >> 3;
    const int b = blockIdx.x >> 9;                 // uniform: 512 blocks/batch

    // own level dims
    const int Wl = 160 >> st;
    const int Hl = (st == 3) ? 12 : (92 >> st);
    const int Sl = (st == 0) ? 0 : (st == 1) ? 14720 : (st == 2) ? 18400 : 19320;

    const ushort* qrow = qp + (size_t)bq * 768;

    // own level's 8 points -> pre-scaled pixel coords
    float px[8], py[8];
    {
        ushort8v uo0 = *(const ushort8v*)(qrow + h * 64 + st * 16);
        ushort8v uo1 = *(const ushort8v*)(qrow + h * 64 + st * 16 + 8);
        float2 rf = *(const float2*)(ref + (size_t)bq * 8 + st * 2);
        const float fW = (float)Wl, fH = (float)Hl;
        #pragma unroll
        for (int i = 0; i < 4; ++i) {
            px[i]     = fmaf(rf.x, fW, h2f(uo0[2 * i]))     - 0.5f;
            py[i]     = fmaf(rf.y, fH, h2f(uo0[2 * i + 1])) - 0.5f;
            px[i + 4] = fmaf(rf.x, fW, h2f(uo1[2 * i]))     - 0.5f;
            py[i + 4] = fmaf(rf.y, fH, h2f(uo1[2 * i + 1])) - 0.5f;
        }
    }

    // fused softmax over 32 logits (8 per lane = own level, width-4 group)
    float a8[8];
    {
        ushort8v ul = *(const ushort8v*)(qrow + 512 + h * 32 + st * 8);
        #pragma unroll
        for (int i = 0; i < 8; ++i) a8[i] = h2f(ul[i]);
        float m = a8[0];
        #pragma unroll
        for (int i = 1; i < 8; ++i) m = fmaxf(m, a8[i]);
        m = fmaxf(m, __shfl_xor(m, 1, 4));
        m = fmaxf(m, __shfl_xor(m, 2, 4));
        float s = 0.f;
        #pragma unroll
        for (int i = 0; i < 8; ++i) { a8[i] = __expf(a8[i] - m); s += a8[i]; }
        s += __shfl_xor(s, 1, 4);
        s += __shfl_xor(s, 2, 4);
        float inv = 1.f / s;
        #pragma unroll
        for (int i = 0; i < 8; ++i) a8[i] *= inv;
    }

    // SGPR-uniform batch base; per-lane (head, channel-slice) byte offset
    const char* vb = (const char*)(v + (size_t)b * (LTOT * EMB));
    const uint32_t coffB = (uint32_t)(h * 64 + st * 16);   // bytes

    float acc[8] = {0.f, 0.f, 0.f, 0.f, 0.f, 0.f, 0.f, 0.f};

    #pragma unroll
    for (int idx = 0; idx < 8; ++idx) {
        // ---- owner math: bilinear weights + row byte-offsets, own point ----
        float px_ = px[idx], py_ = py[idx];
        float x0f = floorf(px_), y0f = floorf(py_);
        float wx = px_ - x0f, wy = py_ - y0f;
        int x0 = (int)x0f, y0 = (int)y0f;
        int x1 = x0 + 1, y1 = y0 + 1;
        float vx0 = ((uint32_t)x0 < (uint32_t)Wl) ? 1.f : 0.f;
        float vx1 = ((uint32_t)x1 < (uint32_t)Wl) ? 1.f : 0.f;
        float vy0 = ((uint32_t)y0 < (uint32_t)Hl) ? 1.f : 0.f;
        float vy1 = ((uint32_t)y1 < (uint32_t)Hl) ? 1.f : 0.f;
        int cx0 = min(max(x0, 0), Wl - 1);
        int cx1 = min(max(x1, 0), Wl - 1);
        int cy0 = min(max(y0, 0), Hl - 1);
        int cy1 = min(max(y1, 0), Hl - 1);
        float aw = a8[idx];
        float omx = 1.f - wx, omy = 1.f - wy;
        float omya = omy * aw, wya = wy * aw;
        float w00 = omx * omya * (vx0 * vy0);
        float w10 = wx  * omya * (vx1 * vy0);
        float w01 = omx * wya  * (vx0 * vy1);
        float w11 = wx  * wya  * (vx1 * vy1);
        int r0 = Sl + cy0 * Wl;
        int r1 = Sl + cy1 * Wl;
        uint32_t e00 = (uint32_t)(r0 + cx0) << 9;   // pixel-row * 512 bytes
        uint32_t e10 = (uint32_t)(r0 + cx1) << 9;
        uint32_t e01 = (uint32_t)(r1 + cx0) << 9;
        uint32_t e11 = (uint32_t)(r1 + cx1) << 9;

        // ---- consume all 4 levels' points (broadcast from lane L) ----
        #define ACCMIX(w_, c_) \
            fmx_lo(acc[0], w_, c_.x); fmx_hi(acc[1], w_, c_.x); \
            fmx_lo(acc[2], w_, c_.y); fmx_hi(acc[3], w_, c_.y); \
            fmx_lo(acc[4], w_, c_.z); fmx_hi(acc[5], w_, c_.z); \
            fmx_lo(acc[6], w_, c_.w); fmx_hi(acc[7], w_, c_.w);
        #define DO_LEVEL(L) { \
            float W00 = bcastf<L>(w00), W10 = bcastf<L>(w10); \
            float W01 = bcastf<L>(w01), W11 = bcastf<L>(w11); \
            uint32_t E00 = bcastu<L>(e00), E10 = bcastu<L>(e10); \
            uint32_t E01 = bcastu<L>(e01), E11 = bcastu<L>(e11); \
            uint4 c00 = *(const uint4*)(vb + (E00 + coffB)); \
            uint4 c10 = *(const uint4*)(vb + (E10 + coffB)); \
            uint4 c01 = *(const uint4*)(vb + (E01 + coffB)); \
            uint4 c11 = *(const uint4*)(vb + (E11 + coffB)); \
            ACCMIX(W00, c00); ACCMIX(W10, c10); \
            ACCMIX(W01, c01); ACCMIX(W11, c11); }
        DO_LEVEL(0)
        DO_LEVEL(1)
        DO_LEVEL(2)
        DO_LEVEL(3)
        #undef DO_LEVEL
        #undef ACCMIX
    }

    ushort8v r;
    #pragma unroll
    for (int i = 0; i < 8; ++i) r[i] = f2bf(acc[i]);
    *(ushort8v*)(agg + (size_t)bq * 256 + h * 32 + st * 8) = r;
}

// ---------------------------------------------------------------------------
// Launch
// ---------------------------------------------------------------------------
extern "C" void kernel_launch(void* const* d_in, const int* in_sizes, int n_in,
                              void* d_out, int out_size, void* d_ws, size_t ws_size,
                              hipStream_t stream) {
    const float* query  = (const float*)d_in[0];
    const float* value  = (const float*)d_in[1];
    const float* refpts = (const float*)d_in[2];
    const float* W_off  = (const float*)d_in[4];
    const float* b_off  = (const float*)d_in[5];
    const float* W_attn = (const float*)d_in[6];
    const float* b_attn = (const float*)d_in[7];
    const float* W_val  = (const float*)d_in[8];
    const float* b_val  = (const float*)d_in[9];
    const float* W_out  = (const float*)d_in[10];
    const float* b_out  = (const float*)d_in[11];
    float* out = (float*)d_out;

    char* ws = (char*)d_ws;
    // layout (bytes):
    ushort* v_bf   = (ushort*)(ws);                     // 117376x256 fp16 = 60,096,512
    ushort* qp     = (ushort*)(ws + 72679424ull);       // 24576x768 f16 = 37,748,736
    ushort* agg_bf = (ushort*)(ws + 148176896ull);      // 24576x256 bf16 = 12,582,912
    ushort* Wvt    = (ushort*)(ws + 160759808ull);      // 131,072
    ushort* Wq     = (ushort*)(ws + 160890880ull);      // 768x256 bf16 = 393,216
    ushort* Wot    = (ushort*)(ws + 161284096ull);      // 131,072
    float*  bcat   = (float*) (ws + 161415168ull);      // 3,072

    // weight preprocessing (4 transposed casts + bias concat, one kernel)
    prep<<<1283, 256, 0, stream>>>(W_val, W_off, W_attn, W_out,
                                   b_off, b_attn, Wvt, Wq, Wot, bcat);

    // 1. v = value @ W_val + b_val -> fp16 (fused fp32 read + cast)
    vgemm<<<ROWS_VP / 128, 512, 0, stream>>>(value, Wvt, b_val, v_bf);

    // 2. qp = query @ [W_off | W_attn] + [b_off | b_attn] -> f16 (fused cast)
    qgemm<<<dim3(ROWS_Q / 128, 6), 256, 0, stream>>>(query, Wq, bcat, qp);

    // 3. sampling + softmax + aggregation -> bf16 agg
    sampler4<<<(ROWS_Q * NH) / 64, 256, 0, stream>>>(
        v_bf, qp, refpts, agg_bf);

    // 4. out = agg @ W_out + b_out (bf16 MFMA, fp32 out)
    gemm_bt<<<dim3(ROWS_Q / 128, 2), 256, 0, stream>>>(
        agg_bf, Wot, b_out, out, ROWS_Q, 256);
}

// Round 6
// 404.833 us; speedup vs baseline: 1.2924x; 1.0454x over previous
//
#include <hip/hip_runtime.h>
#include <hip/hip_fp16.h>
#include <stdint.h>

// Problem constants
#define BS 6
#define NQ 4096
#define NH 8
#define EMB 256
#define LTOT 19560
#define ROWS_V 117360
#define ROWS_VP 117376          // padded to 917*128
#define ROWS_Q 24576            // 192*128
#define VBLK 917                // vgemm blocks in front kernel
#define QBLK 1152               // qgemm blocks in front kernel

typedef __attribute__((ext_vector_type(8))) short bf16x8;
typedef __attribute__((ext_vector_type(4))) float floatx4;
typedef __attribute__((ext_vector_type(8))) unsigned short ushort8v;

__device__ __forceinline__ ushort f2bf(float f) {
    union { float f; uint32_t i; } c; c.f = f;
    uint32_t r = c.i + 0x7FFFu + ((c.i >> 16) & 1u);   // round-to-nearest-even
    return (ushort)(r >> 16);
}
__device__ __forceinline__ ushort f2h(float f) {
    __half h = __float2half(f);                        // RTE
    union { __half h; ushort u; } c; c.h = h; return c.u;
}
__device__ __forceinline__ float h2f(ushort u) {
    union { ushort u; __half h; } c; c.u = u; return __half2float(c.h);
}

__device__ __forceinline__ void gll16(const ushort* g, ushort* l) {
    __builtin_amdgcn_global_load_lds(
        (const __attribute__((address_space(1))) void*)g,
        (__attribute__((address_space(3))) void*)l, 16, 0, 0);
}

// compile-time broadcast of lane L (within each 4-lane group) via ds_swizzle
template<int L>
__device__ __forceinline__ float bcastf(float x) {
    return __int_as_float(
        __builtin_amdgcn_ds_swizzle(__float_as_int(x), 0x1C | (L << 5)));
}
template<int L>
__device__ __forceinline__ uint32_t bcastu(uint32_t x) {
    return (uint32_t)__builtin_amdgcn_ds_swizzle((int)x, 0x1C | (L << 5));
}

// gfx950 mixed-precision FMA: acc = f32(w) * f16half(u) + acc
__device__ __forceinline__ void fmx_lo(float& acc, float w, uint32_t u) {
    asm("v_fma_mix_f32 %0, %1, %2, %0 op_sel:[0,0,0] op_sel_hi:[0,1,0]"
        : "+v"(acc) : "v"(w), "v"(u));
}
__device__ __forceinline__ void fmx_hi(float& acc, float w, uint32_t u) {
    asm("v_fma_mix_f32 %0, %1, %2, %0 op_sel:[0,1,0] op_sel_hi:[0,1,0]"
        : "+v"(acc) : "v"(w), "v"(u));
}

// ---------------------------------------------------------------------------
// Fused weight prep: all 4 transposed-cast weights + bias concat, 1 kernel.
// ---------------------------------------------------------------------------
__global__ __launch_bounds__(256) void prep(
    const float* __restrict__ W_val, const float* __restrict__ W_off,
    const float* __restrict__ W_attn, const float* __restrict__ W_out,
    const float* __restrict__ b_off, const float* __restrict__ b_attn,
    ushort* __restrict__ Wvt, ushort* __restrict__ Wq,
    ushort* __restrict__ Wot, float* __restrict__ bcat)
{
    int id = blockIdx.x * 256 + threadIdx.x;
    if (id < 65536) {
        int n = id >> 8, k = id & 255;
        Wvt[id] = f2bf(W_val[k * 256 + n]);
        return;
    }
    id -= 65536;
    if (id < 131072) {
        int n = id >> 8, k = id & 255;
        Wq[id] = f2bf(W_off[k * 512 + n]);
        return;
    }
    id -= 131072;
    if (id < 65536) {
        int n = id >> 8, k = id & 255;
        Wq[131072 + id] = f2bf(W_attn[k * 256 + n]);
        return;
    }
    id -= 65536;
    if (id < 65536) {
        int n = id >> 8, k = id & 255;
        Wot[id] = f2bf(W_out[k * 256 + n]);
        return;
    }
    id -= 65536;
    if (id < 768) bcat[id] = (id < 512) ? b_off[id] : b_attn[id - 512];
}

// ---------------------------------------------------------------------------
// Unified front GEMM kernel (512 threads = 8 waves):
//  blocks [0, VBLK):        v = value(fp32) @ Wvt^T + b_val -> fp16
//                           tile 128(M) x 256(N), waves 2x4, acc[4][4]
//  blocks [VBLK, VBLK+QBLK): qp = query(fp32) @ Wq^T + bcat -> f16
//                           tile 128(M) x 128(N), waves 4x2, acc[2][4]
// Both: A fp32 global -> reg cast bf16 -> LDS; B bf16 via global_load_lds.
// ---------------------------------------------------------------------------
__global__ __launch_bounds__(512) void front(
    const float* __restrict__ value,  // ROWS_V x 256 fp32
    const float* __restrict__ query,  // ROWS_Q x 256 fp32
    const ushort* __restrict__ Wvt,   // 256 x 256 bf16
    const ushort* __restrict__ Wq,    // 768 x 256 bf16
    const float* __restrict__ b_val,  // 256
    const float* __restrict__ bcat,   // 768
    ushort* __restrict__ v_out,       // ROWS_VP x 256 fp16
    ushort* __restrict__ qp_out)      // ROWS_Q x 768 f16
{
    constexpr int K = 256;
    __shared__ ushort As[128 * 32];
    __shared__ ushort Bs[256 * 32];

    const int t = threadIdx.x;
    const int w = t >> 6;
    const int lane = t & 63;
    const int bid = blockIdx.x;

    if (bid < VBLK) {
        // ---------------- vgemm role ----------------
        constexpr int N = 256, M = ROWS_V;
        const int bm = bid * 128;
        const int wm = (w >> 2) * 64;
        const int wn = (w & 3) * 64;

        const int arow = t >> 2;
        const int acol = (t & 3) * 8;
        const bool rowok = (bm + arow) < M;
        const float* Ap = value + (size_t)(bm + arow) * K + acol;
        ushort* Asw = &As[arow * 32 + acol];

        const int srow = lane >> 2;
        const int scol = (lane & 3) * 8;
        const ushort* Bg0 = Wvt + (size_t)(w * 32 + srow) * K + scol;
        const ushort* Bg1 = Wvt + (size_t)(w * 32 + 16 + srow) * K + scol;
        ushort* Bl0 = &Bs[(w * 32) * 32];
        ushort* Bl1 = &Bs[(w * 32 + 16) * 32];

        const ushort* apt = &As[(wm + (lane & 15)) * 32 + (lane >> 4) * 8];
        const ushort* bpt = &Bs[(wn + (lane & 15)) * 32 + (lane >> 4) * 8];

        floatx4 acc[4][4] = {};

        for (int kt = 0; kt < K; kt += 32) {
            float4 f0, f1;
            if (rowok) {
                f0 = *(const float4*)(Ap + kt);
                f1 = *(const float4*)(Ap + kt + 4);
            } else {
                f0 = make_float4(0.f, 0.f, 0.f, 0.f);
                f1 = f0;
            }
            __syncthreads();
            gll16(Bg0 + kt, Bl0);
            gll16(Bg1 + kt, Bl1);
            ushort8v u;
            u[0] = f2bf(f0.x); u[1] = f2bf(f0.y); u[2] = f2bf(f0.z); u[3] = f2bf(f0.w);
            u[4] = f2bf(f1.x); u[5] = f2bf(f1.y); u[6] = f2bf(f1.z); u[7] = f2bf(f1.w);
            *(ushort8v*)Asw = u;
            __syncthreads();

            bf16x8 a[4], b[4];
            #pragma unroll
            for (int i = 0; i < 4; ++i) {
                a[i] = *(const bf16x8*)(apt + i * 16 * 32);
                b[i] = *(const bf16x8*)(bpt + i * 16 * 32);
            }
            #pragma unroll
            for (int i = 0; i < 4; ++i)
                #pragma unroll
                for (int j = 0; j < 4; ++j)
                    acc[i][j] = __builtin_amdgcn_mfma_f32_16x16x32_bf16(
                        a[i], b[j], acc[i][j], 0, 0, 0);
        }

        const int crow = (lane >> 4) * 4;
        const int ccol = lane & 15;
        #pragma unroll
        for (int j = 0; j < 4; ++j) {
            int gcol = wn + j * 16 + ccol;
            float bv = b_val[gcol];
            #pragma unroll
            for (int i = 0; i < 4; ++i) {
                #pragma unroll
                for (int r = 0; r < 4; ++r) {
                    int grow = bm + wm + i * 16 + crow + r;
                    if (grow < M)
                        v_out[(size_t)grow * N + gcol] = f2h(acc[i][j][r] + bv);
                }
            }
        }
    } else {
        // ---------------- qgemm role ----------------
        constexpr int N = 768;
        const int qbid = bid - VBLK;
        const int bm = (qbid % 192) * 128;
        const int bn = (qbid / 192) * 128;
        const int wm = (w >> 1) * 32;      // waves 4(M) x 2(N)
        const int wn = (w & 1) * 64;

        const int arow = t >> 2;
        const int acol = (t & 3) * 8;
        const float* Ap = query + (size_t)(bm + arow) * K + acol;
        ushort* Asw = &As[arow * 32 + acol];

        // B staging: wave w stages rows [16w, 16w+16), 4 chunks/row
        const int srow = lane >> 2;
        const int scol = (lane & 3) * 8;
        const ushort* Bg0 = Wq + (size_t)(bn + w * 16 + srow) * K + scol;
        ushort* Bl0 = &Bs[(w * 16) * 32];

        const ushort* apt = &As[(wm + (lane & 15)) * 32 + (lane >> 4) * 8];
        const ushort* bpt = &Bs[(wn + (lane & 15)) * 32 + (lane >> 4) * 8];

        floatx4 acc[2][4] = {};

        for (int kt = 0; kt < K; kt += 32) {
            float4 f0 = *(const float4*)(Ap + kt);
            float4 f1 = *(const float4*)(Ap + kt + 4);
            __syncthreads();
            gll16(Bg0 + kt, Bl0);
            ushort8v u;
            u[0] = f2bf(f0.x); u[1] = f2bf(f0.y); u[2] = f2bf(f0.z); u[3] = f2bf(f0.w);
            u[4] = f2bf(f1.x); u[5] = f2bf(f1.y); u[6] = f2bf(f1.z); u[7] = f2bf(f1.w);
            *(ushort8v*)Asw = u;
            __syncthreads();

            bf16x8 a[2], b[4];
            #pragma unroll
            for (int i = 0; i < 2; ++i)
                a[i] = *(const bf16x8*)(apt + i * 16 * 32);
            #pragma unroll
            for (int j = 0; j < 4; ++j)
                b[j] = *(const bf16x8*)(bpt + j * 16 * 32);
            #pragma unroll
            for (int i = 0; i < 2; ++i)
                #pragma unroll
                for (int j = 0; j < 4; ++j)
                    acc[i][j] = __builtin_amdgcn_mfma_f32_16x16x32_bf16(
                        a[i], b[j], acc[i][j], 0, 0, 0);
        }

        const int crow = (lane >> 4) * 4;
        const int ccol = lane & 15;
        #pragma unroll
        for (int j = 0; j < 4; ++j) {
            int gcol = bn + wn + j * 16 + ccol;
            float bv = bcat[gcol];
            #pragma unroll
            for (int i = 0; i < 2; ++i) {
                int grow = bm + wm + i * 16 + crow;
                #pragma unroll
                for (int r = 0; r < 4; ++r)
                    qp_out[(size_t)(grow + r) * N + gcol] = f2h(acc[i][j][r] + bv);
            }
        }
    }
}

// ---------------------------------------------------------------------------
// bf16 MFMA GEMM (m97 structure): C[M,N] = A[M,256] @ Bt[N,256]^T + bias
// fp32 output. 128x128 tile, 256 threads = 4 waves.  (out projection)
// ---------------------------------------------------------------------------
__global__ __launch_bounds__(256) void gemm_bt(
    const ushort* __restrict__ A,    // Mpad x 256 bf16
    const ushort* __restrict__ Bt,   // N x 256 bf16
    const float* __restrict__ bias,  // N
    float* __restrict__ C, int M, int N)
{
    constexpr int K = 256;
    __shared__ ushort As[128 * 32];
    __shared__ ushort Bs[128 * 32];

    const int t = threadIdx.x;
    const int w = t >> 6;
    const int lane = t & 63;
    const int bm = blockIdx.x * 128;
    const int bn = blockIdx.y * 128;
    const int wm = (w >> 1) * 64;
    const int wn = (w & 1) * 64;

    floatx4 acc[4][4] = {};

    const int srow = lane >> 2;
    const int scol = (lane & 3) * 8;
    const ushort* Ag0 = A + (size_t)(bm + (w * 2 + 0) * 16 + srow) * K + scol;
    const ushort* Ag1 = A + (size_t)(bm + (w * 2 + 1) * 16 + srow) * K + scol;
    const ushort* Bg0 = Bt + (size_t)(bn + (w * 2 + 0) * 16 + srow) * K + scol;
    const ushort* Bg1 = Bt + (size_t)(bn + (w * 2 + 1) * 16 + srow) * K + scol;
    ushort* Al0 = &As[(w * 2 + 0) * 512];
    ushort* Al1 = &As[(w * 2 + 1) * 512];
    ushort* Bl0 = &Bs[(w * 2 + 0) * 512];
    ushort* Bl1 = &Bs[(w * 2 + 1) * 512];

    const ushort* apt = &As[(wm + (lane & 15)) * 32 + (lane >> 4) * 8];
    const ushort* bpt = &Bs[(wn + (lane & 15)) * 32 + (lane >> 4) * 8];

    for (int kt = 0; kt < K; kt += 32) {
        __syncthreads();
        gll16(Ag0 + kt, Al0);
        gll16(Ag1 + kt, Al1);
        gll16(Bg0 + kt, Bl0);
        gll16(Bg1 + kt, Bl1);
        __syncthreads();

        bf16x8 a[4], b[4];
        #pragma unroll
        for (int i = 0; i < 4; ++i) {
            a[i] = *(const bf16x8*)(apt + i * 16 * 32);
            b[i] = *(const bf16x8*)(bpt + i * 16 * 32);
        }
        #pragma unroll
        for (int i = 0; i < 4; ++i)
            #pragma unroll
            for (int j = 0; j < 4; ++j)
                acc[i][j] = __builtin_amdgcn_mfma_f32_16x16x32_bf16(
                    a[i], b[j], acc[i][j], 0, 0, 0);
    }

    const int crow = (lane >> 4) * 4;
    const int ccol = lane & 15;
    #pragma unroll
    for (int j = 0; j < 4; ++j) {
        int gcol = bn + wn + j * 16 + ccol;
        float bv = bias[gcol];
        #pragma unroll
        for (int i = 0; i < 4; ++i) {
            #pragma unroll
            for (int r = 0; r < 4; ++r) {
                int grow = bm + wm + i * 16 + crow + r;
                if (grow < M)
                    C[(size_t)grow * N + gcol] = acc[i][j][r] + bv;
            }
        }
    }
}

// ---------------------------------------------------------------------------
// Deformable sampling + aggregation (owner-computes + fma_mix + saddr),
// (pixel, 256ch) fp16 v layout. 48 KB LDS ballast caps residency at
// 3 blocks/CU. XCD-chunked block swizzle: each XCD gets a contiguous
// 384-block logical window (0.75 batch) -> smaller per-L2 v working set.
// qp is f16 (1536 B/row): [0:512) offsets, [512:768) logits.
// ---------------------------------------------------------------------------
__global__ __launch_bounds__(256) void sampler4(
    const ushort* __restrict__ v,    // (BS, LTOT, 256) fp16
    const ushort* __restrict__ qp,   // (BS*NQ, 768) f16
    const float* __restrict__ ref,   // (BS*NQ, 4, 2)
    ushort* __restrict__ agg)        // (BS*NQ, 256) bf16
{
    __shared__ char ballast[49152];          // occupancy cap: 3 blocks/CU
    if (blockIdx.x > 0x7FFFFFF0u) {          // never true; unprovable -> kept
        ballast[threadIdx.x] = (char)threadIdx.x;
        agg[0] = (ushort)ballast[(threadIdx.x * 37) & 4095];
    }

    // XCD-chunked swizzle: 3072 blocks = 8 XCDs * 384; bijective
    const int bid = (blockIdx.x & 7) * 384 + (blockIdx.x >> 3);

    const int tid = threadIdx.x;
    const int g = bid * 64 + (tid >> 2);          // (b*NQ+q)*8 + h
    const int st = tid & 3;                        // this lane owns level st
    const int h = g & 7;
    const int bq = g >> 3;
    const int b = bid >> 9;                        // 512 blocks/batch

    // own level dims
    const int Wl = 160 >> st;
    const int Hl = (st == 3) ? 12 : (92 >> st);
    const int Sl = (st == 0) ? 0 : (st == 1) ? 14720 : (st == 2) ? 18400 : 19320;

    const ushort* qrow = qp + (size_t)bq * 768;

    // own level's 8 points -> pre-scaled pixel coords
    float px[8], py[8];
    {
        ushort8v uo0 = *(const ushort8v*)(qrow + h * 64 + st * 16);
        ushort8v uo1 = *(const ushort8v*)(qrow + h * 64 + st * 16 + 8);
        float2 rf = *(const float2*)(ref + (size_t)bq * 8 + st * 2);
        const float fW = (float)Wl, fH = (float)Hl;
        #pragma unroll
        for (int i = 0; i < 4; ++i) {
            px[i]     = fmaf(rf.x, fW, h2f(uo0[2 * i]))     - 0.5f;
            py[i]     = fmaf(rf.y, fH, h2f(uo0[2 * i + 1])) - 0.5f;
            px[i + 4] = fmaf(rf.x, fW, h2f(uo1[2 * i]))     - 0.5f;
            py[i + 4] = fmaf(rf.y, fH, h2f(uo1[2 * i + 1])) - 0.5f;
        }
    }

    // fused softmax over 32 logits (8 per lane = own level, width-4 group)
    float a8[8];
    {
        ushort8v ul = *(const ushort8v*)(qrow + 512 + h * 32 + st * 8);
        #pragma unroll
        for (int i = 0; i < 8; ++i) a8[i] = h2f(ul[i]);
        float m = a8[0];
        #pragma unroll
        for (int i = 1; i < 8; ++i) m = fmaxf(m, a8[i]);
        m = fmaxf(m, __shfl_xor(m, 1, 4));
        m = fmaxf(m, __shfl_xor(m, 2, 4));
        float s = 0.f;
        #pragma unroll
        for (int i = 0; i < 8; ++i) { a8[i] = __expf(a8[i] - m); s += a8[i]; }
        s += __shfl_xor(s, 1, 4);
        s += __shfl_xor(s, 2, 4);
        float inv = 1.f / s;
        #pragma unroll
        for (int i = 0; i < 8; ++i) a8[i] *= inv;
    }

    // SGPR-uniform batch base; per-lane (head, channel-slice) byte offset
    const char* vb = (const char*)(v + (size_t)b * (LTOT * EMB));
    const uint32_t coffB = (uint32_t)(h * 64 + st * 16);   // bytes

    float acc[8] = {0.f, 0.f, 0.f, 0.f, 0.f, 0.f, 0.f, 0.f};

    #pragma unroll
    for (int idx = 0; idx < 8; ++idx) {
        // ---- owner math: bilinear weights + row byte-offsets, own point ----
        float px_ = px[idx], py_ = py[idx];
        float x0f = floorf(px_), y0f = floorf(py_);
        float wx = px_ - x0f, wy = py_ - y0f;
        int x0 = (int)x0f, y0 = (int)y0f;
        int x1 = x0 + 1, y1 = y0 + 1;
        float vx0 = ((uint32_t)x0 < (uint32_t)Wl) ? 1.f : 0.f;
        float vx1 = ((uint32_t)x1 < (uint32_t)Wl) ? 1.f : 0.f;
        float vy0 = ((uint32_t)y0 < (uint32_t)Hl) ? 1.f : 0.f;
        float vy1 = ((uint32_t)y1 < (uint32_t)Hl) ? 1.f : 0.f;
        int cx0 = min(max(x0, 0), Wl - 1);
        int cx1 = min(max(x1, 0), Wl - 1);
        int cy0 = min(max(y0, 0), Hl - 1);
        int cy1 = min(max(y1, 0), Hl - 1);
        float aw = a8[idx];
        float omx = 1.f - wx, omy = 1.f - wy;
        float omya = omy * aw, wya = wy * aw;
        float w00 = omx * omya * (vx0 * vy0);
        float w10 = wx  * omya * (vx1 * vy0);
        float w01 = omx * wya  * (vx0 * vy1);
        float w11 = wx  * wya  * (vx1 * vy1);
        int r0 = Sl + cy0 * Wl;
        int r1 = Sl + cy1 * Wl;
        uint32_t e00 = (uint32_t)(r0 + cx0) << 9;   // pixel-row * 512 bytes
        uint32_t e10 = (uint32_t)(r0 + cx1) << 9;
        uint32_t e01 = (uint32_t)(r1 + cx0) << 9;
        uint32_t e11 = (uint32_t)(r1 + cx1) << 9;

        // ---- consume all 4 levels' points (broadcast from lane L) ----
        #define ACCMIX(w_, c_) \
            fmx_lo(acc[0], w_, c_.x); fmx_hi(acc[1], w_, c_.x); \
            fmx_lo(acc[2], w_, c_.y); fmx_hi(acc[3], w_, c_.y); \
            fmx_lo(acc[4], w_, c_.z); fmx_hi(acc[5], w_, c_.z); \
            fmx_lo(acc[6], w_, c_.w); fmx_hi(acc[7], w_, c_.w);
        #define DO_LEVEL(L) { \
            float W00 = bcastf<L>(w00), W10 = bcastf<L>(w10); \
            float W01 = bcastf<L>(w01), W11 = bcastf<L>(w11); \
            uint32_t E00 = bcastu<L>(e00), E10 = bcastu<L>(e10); \
            uint32_t E01 = bcastu<L>(e01), E11 = bcastu<L>(e11); \
            uint4 c00 = *(const uint4*)(vb + (E00 + coffB)); \
            uint4 c10 = *(const uint4*)(vb + (E10 + coffB)); \
            uint4 c01 = *(const uint4*)(vb + (E01 + coffB)); \
            uint4 c11 = *(const uint4*)(vb + (E11 + coffB)); \
            ACCMIX(W00, c00); ACCMIX(W10, c10); \
            ACCMIX(W01, c01); ACCMIX(W11, c11); }
        DO_LEVEL(0)
        DO_LEVEL(1)
        DO_LEVEL(2)
        DO_LEVEL(3)
        #undef DO_LEVEL
        #undef ACCMIX
    }

    ushort8v r;
    #pragma unroll
    for (int i = 0; i < 8; ++i) r[i] = f2bf(acc[i]);
    *(ushort8v*)(agg + (size_t)bq * 256 + h * 32 + st * 8) = r;
}

// ---------------------------------------------------------------------------
// Launch
// ---------------------------------------------------------------------------
extern "C" void kernel_launch(void* const* d_in, const int* in_sizes, int n_in,
                              void* d_out, int out_size, void* d_ws, size_t ws_size,
                              hipStream_t stream) {
    const float* query  = (const float*)d_in[0];
    const float* value  = (const float*)d_in[1];
    const float* refpts = (const float*)d_in[2];
    const float* W_off  = (const float*)d_in[4];
    const float* b_off  = (const float*)d_in[5];
    const float* W_attn = (const float*)d_in[6];
    const float* b_attn = (const float*)d_in[7];
    const float* W_val  = (const float*)d_in[8];
    const float* b_val  = (const float*)d_in[9];
    const float* W_out  = (const float*)d_in[10];
    const float* b_out  = (const float*)d_in[11];
    float* out = (float*)d_out;

    char* ws = (char*)d_ws;
    // layout (bytes):
    ushort* v_bf   = (ushort*)(ws);                     // 117376x256 fp16 = 60,096,512
    ushort* qp     = (ushort*)(ws + 72679424ull);       // 24576x768 f16 = 37,748,736
    ushort* agg_bf = (ushort*)(ws + 148176896ull);      // 24576x256 bf16 = 12,582,912
    ushort* Wvt    = (ushort*)(ws + 160759808ull);      // 131,072
    ushort* Wq     = (ushort*)(ws + 160890880ull);      // 768x256 bf16 = 393,216
    ushort* Wot    = (ushort*)(ws + 161284096ull);      // 131,072
    float*  bcat   = (float*) (ws + 161415168ull);      // 3,072

    // weight preprocessing (4 transposed casts + bias concat, one kernel)
    prep<<<1283, 256, 0, stream>>>(W_val, W_off, W_attn, W_out,
                                   b_off, b_attn, Wvt, Wq, Wot, bcat);

    // 1+2. v GEMM and qp GEMM in one launch (independent work, overlapped)
    front<<<VBLK + QBLK, 512, 0, stream>>>(
        value, query, Wvt, Wq, b_val, bcat, v_bf, qp);

    // 3. sampling + softmax + aggregation -> bf16 agg
    sampler4<<<(ROWS_Q * NH) / 64, 256, 0, stream>>>(
        v_bf, qp, refpts, agg_bf);

    // 4. out = agg @ W_out + b_out (bf16 MFMA, fp32 out)
    gemm_bt<<<dim3(ROWS_Q / 128, 2), 256, 0, stream>>>(
        agg_bf, Wot, b_out, out, ROWS_Q, 256);
}